// Round 5
// baseline (305.548 us; speedup 1.0000x reference)
//
#include <hip/hip_runtime.h>
#include <math.h>

#define NB 64      // batch N
#define LL 128     // n_in capsules
#define DD 768     // feature dim
#define ID 64      // in_dim
#define OD 64      // out_dim
#define NO 32      // n_out
#define EPSF 1e-8f

// ws layout (floats):
//  V       : NB*LL*NO*OD = 16777216  [n][l][o*64+j]
//    Cpart : 6*524288 = 3145728  (aliases V front; consumed by k0b pre-k1)
//    apart : 6*8192   = 49152    (aliases V;      consumed by k0c pre-k1)
//  mu_in_T : LL*ID*NB = 524288   [l][i][n]  (dead after k1)
//    dnp   : 16*NB*NO = 32768    (aliases mu_in_T; written by k3 post-k1)
//    aUp   : 32768               (aliases mu_in_T+32768)
//  f_a     : LL*NB = 8192        [l][n]
//  S1p     : 16*NB*NO*OD = 2097152  chunk partials [c][n][o][j]
//  S2p     : 2097152
//  mu_s    : NB*NO*OD = 131072   [n][o*64+j]
//  i2v_s   : 131072
//  cterm   : NB*NO = 2048

__device__ __forceinline__ float gelu_exact(float v) {
  return 0.5f * v * (1.0f + erff(v * 0.70710678118654752440f));
}
__device__ __forceinline__ float sigmoidf_(float z) {
  return 1.0f / (1.0f + __expf(-z));
}

// ---------------- k0a: split-K partial GEMM for the projections.
// grid 768 = (l:128, kc:6); 64n x 64i tile, K-slice of 128.
__global__ __launch_bounds__(256) void k0a_proj(
    const float* __restrict__ x, const float* __restrict__ Wscore,
    const float* __restrict__ Wcap,
    float* __restrict__ Cpart, float* __restrict__ apart)
{
  const int l  = blockIdx.x & 127;
  const int kc = blockIdx.x >> 7;
  const int t = threadIdx.x;
  const int tn = t >> 4;
  const int ti = t & 15;
  __shared__ float Xs[64][68];
  __shared__ float Ws[64][68];
  __shared__ float Ss[64];
  float C[4][4] = {{0.f}};
  float asum[4] = {0.f, 0.f, 0.f, 0.f};

  for (int kt = 0; kt < 2; ++kt) {
    const int kbase = kc * 128 + kt * 64;
#pragma unroll
    for (int r = 0; r < 4; ++r) {
      const int flat = r * 1024 + t * 4;
      const int p = flat >> 6, qq = flat & 63;
      *(float4*)&Xs[p][qq] = *(const float4*)&x[(p * LL + l) * DD + kbase + qq];
      *(float4*)&Ws[p][qq] = *(const float4*)&Wcap[(l * DD + kbase + p) * ID + qq];
    }
    if (t < 16)
      *(float4*)&Ss[4 * t] = *(const float4*)&Wscore[l * DD + kbase + 4 * t];
    __syncthreads();
#pragma unroll 8
    for (int k = 0; k < 64; ++k) {
      float av[4];
      av[0] = Xs[4 * tn + 0][k];
      av[1] = Xs[4 * tn + 1][k];
      av[2] = Xs[4 * tn + 2][k];
      av[3] = Xs[4 * tn + 3][k];
      const float4 b = *(const float4*)&Ws[k][4 * ti];
      const float sk = Ss[k];
#pragma unroll
      for (int a = 0; a < 4; ++a) {
        C[a][0] = fmaf(av[a], b.x, C[a][0]);
        C[a][1] = fmaf(av[a], b.y, C[a][1]);
        C[a][2] = fmaf(av[a], b.z, C[a][2]);
        C[a][3] = fmaf(av[a], b.w, C[a][3]);
        asum[a] = fmaf(av[a], sk, asum[a]);
      }
    }
    __syncthreads();
  }
#pragma unroll
  for (int a = 0; a < 4; ++a)
    *(float4*)&Cpart[kc * 524288 + (l * 64 + 4 * tn + a) * 64 + 4 * ti] =
        make_float4(C[a][0], C[a][1], C[a][2], C[a][3]);
  if (ti == 0) {   // asum complete per K-slice in every ti-thread; no reduce
#pragma unroll
    for (int a = 0; a < 4; ++a)
      apart[kc * 8192 + l * 64 + 4 * tn + a] = asum[a];
  }
}

// ---------------- k0b: reduce 6 K-partials + bias + gelu -> mu_in_T [l][i][n]
// grid 128 (one per l), 256 threads, LDS transpose.
__global__ __launch_bounds__(256) void k0b_reduce(
    const float* __restrict__ Cpart, const float* __restrict__ Bcap,
    float* __restrict__ mu_in_T)
{
  const int l = blockIdx.x;
  const int t = threadIdx.x;
  __shared__ float T[64][65];
  const int n = t >> 2, i0 = (t & 3) * 16;
#pragma unroll
  for (int g = 0; g < 4; ++g) {
    const int e = l * 4096 + n * 64 + i0 + 4 * g;
    float4 s = *(const float4*)&Cpart[e];
#pragma unroll
    for (int kc = 1; kc < 6; ++kc) {
      const float4 p = *(const float4*)&Cpart[kc * 524288 + e];
      s.x += p.x; s.y += p.y; s.z += p.z; s.w += p.w;
    }
    const float4 bc = *(const float4*)&Bcap[l * 64 + i0 + 4 * g];
    T[n][i0 + 4 * g + 0] = gelu_exact(s.x + bc.x);
    T[n][i0 + 4 * g + 1] = gelu_exact(s.y + bc.y);
    T[n][i0 + 4 * g + 2] = gelu_exact(s.z + bc.z);
    T[n][i0 + 4 * g + 3] = gelu_exact(s.w + bc.w);
  }
  __syncthreads();
  const int i = t >> 2, n0 = (t & 3) * 16;
#pragma unroll
  for (int g = 0; g < 4; ++g) {
    float4 o4;
    o4.x = T[n0 + 4 * g + 0][i];
    o4.y = T[n0 + 4 * g + 1][i];
    o4.z = T[n0 + 4 * g + 2][i];
    o4.w = T[n0 + 4 * g + 3][i];
    *(float4*)&mu_in_T[l * 4096 + i * 64 + n0 + 4 * g] = o4;
  }
}

// ---------------- k0c: reduce asum partials + Bscore -> f_a (sigmoid)
__global__ __launch_bounds__(256) void k0c_fa(
    const float* __restrict__ apart, const float* __restrict__ Bscore,
    float* __restrict__ f_a)
{
  const int e = blockIdx.x * 256 + threadIdx.x;
  float s = 0.f;
#pragma unroll
  for (int kc = 0; kc < 6; ++kc) s += apart[kc * 8192 + e];
  const int l = e >> 6;
  f_a[e] = sigmoidf_(s + Bscore[l]);
}

// ---------------- k1: V[l,o] = mu_in[l] @ Wvote[l,o] + Bvote (fp32), fused
// iter-1 accumulation with uniform R=1/NO.  grid 512 = (o:32, c:16 of 8 l's).
// A staged from mu_in_T so inner loop is 2x ds_read_b128 (VALU-bound).
__global__ __launch_bounds__(256) void k1_votes(
    const float* __restrict__ mu_in_T, const float* __restrict__ Wvote,
    const float* __restrict__ Bvote, const float* __restrict__ f_a,
    float* __restrict__ V, float* __restrict__ S1p, float* __restrict__ S2p)
{
  const int o = blockIdx.x & 31;
  const int c = blockIdx.x >> 5;   // 0..15
  const int t = threadIdx.x;
  const int tn = t >> 4, tj = t & 15;
  __shared__ float As[64][68];   // [k][n]
  __shared__ float Bs[64][68];   // [k][j]
  float s1[4][4] = {{0.f}}, s2acc[4][4] = {{0.f}};

  for (int l = c * 8; l < c * 8 + 8; ++l) {
#pragma unroll
    for (int r = 0; r < 4; ++r) {
      const int flat = r * 1024 + t * 4;
      const int p = flat >> 6, qq = flat & 63;
      *(float4*)&As[p][qq] = *(const float4*)&mu_in_T[l * 4096 + p * 64 + qq];
      *(float4*)&Bs[p][qq] = *(const float4*)&Wvote[((l * NO + o) * ID + p) * OD + qq];
    }
    __syncthreads();
    float C[4][4] = {{0.f}};
#pragma unroll 8
    for (int k = 0; k < 64; ++k) {
      const float4 a4 = *(const float4*)&As[k][4 * tn];
      const float4 b4 = *(const float4*)&Bs[k][4 * tj];
      const float av[4] = {a4.x, a4.y, a4.z, a4.w};
#pragma unroll
      for (int a = 0; a < 4; ++a) {
        C[a][0] = fmaf(av[a], b4.x, C[a][0]);
        C[a][1] = fmaf(av[a], b4.y, C[a][1]);
        C[a][2] = fmaf(av[a], b4.z, C[a][2]);
        C[a][3] = fmaf(av[a], b4.w, C[a][3]);
      }
    }
    __syncthreads();
    const float4 bv = *(const float4*)&Bvote[(l * NO + o) * OD + 4 * tj];
    float wN[4];
#pragma unroll
    for (int a = 0; a < 4; ++a)
      wN[a] = f_a[l * NB + 4 * tn + a] * (1.0f / NO);
#pragma unroll
    for (int a = 0; a < 4; ++a) {
      float4 vv;
      vv.x = C[a][0] + bv.x;
      vv.y = C[a][1] + bv.y;
      vv.z = C[a][2] + bv.z;
      vv.w = C[a][3] + bv.w;
      *(float4*)&V[((4 * tn + a) * LL + l) * (NO * OD) + o * OD + 4 * tj] = vv;
      s1[a][0] = fmaf(wN[a], vv.x, s1[a][0]);
      s1[a][1] = fmaf(wN[a], vv.y, s1[a][1]);
      s1[a][2] = fmaf(wN[a], vv.z, s1[a][2]);
      s1[a][3] = fmaf(wN[a], vv.w, s1[a][3]);
      s2acc[a][0] = fmaf(wN[a] * vv.x, vv.x, s2acc[a][0]);
      s2acc[a][1] = fmaf(wN[a] * vv.y, vv.y, s2acc[a][1]);
      s2acc[a][2] = fmaf(wN[a] * vv.z, vv.z, s2acc[a][2]);
      s2acc[a][3] = fmaf(wN[a] * vv.w, vv.w, s2acc[a][3]);
    }
  }
#pragma unroll
  for (int a = 0; a < 4; ++a) {
    const int base = ((c * NB + 4 * tn + a) * NO + o) * OD + 4 * tj;
    *(float4*)&S1p[base] = make_float4(s1[a][0], s1[a][1], s1[a][2], s1[a][3]);
    *(float4*)&S2p[base] = make_float4(s2acc[a][0], s2acc[a][1], s2acc[a][2], s2acc[a][3]);
  }
}

// ---------------- k2: finalize iter 1 (uniform R).  grid 64 (per n), 256 thr
__global__ __launch_bounds__(256) void k2_fin1(
    const float* __restrict__ S1p, const float* __restrict__ S2p,
    const float* __restrict__ f_a, const float* __restrict__ beta_use,
    const float* __restrict__ beta_ign,
    float* __restrict__ mu_s, float* __restrict__ i2v_s, float* __restrict__ cterm)
{
  const int n = blockIdx.x;
  const int t = threadIdx.x;
  const int o = t >> 3, q = t & 7;
  const int j0 = q * 8;
  __shared__ float rA[128], rB[128];
  if (t < 128) {
    const float fv = f_a[t * NB + n];
    rA[t] = fv;
    rB[t] = beta_use[t] * fv;
  }
  __syncthreads();
  for (int s = 64; s >= 1; s >>= 1) {
    if (t < s) { rA[t] += rA[t + s]; rB[t] += rB[t + s]; }
    __syncthreads();
  }
  const float Fsum = rA[0], BUsum = rB[0];
  const float S0 = Fsum * (1.0f / NO);
  const float denom = S0 + EPSF;
  const float inv_den = 1.0f / denom;

  float S1[8], S2[8];
#pragma unroll
  for (int k = 0; k < 8; ++k) { S1[k] = 0.f; S2[k] = 0.f; }
  for (int cc = 0; cc < 16; ++cc) {
    const int base = ((cc * NB + n) * NO + o) * OD + j0;
    const float4 u0 = *(const float4*)&S1p[base];
    const float4 u1 = *(const float4*)&S1p[base + 4];
    const float4 w0 = *(const float4*)&S2p[base];
    const float4 w1 = *(const float4*)&S2p[base + 4];
    S1[0] += u0.x; S1[1] += u0.y; S1[2] += u0.z; S1[3] += u0.w;
    S1[4] += u1.x; S1[5] += u1.y; S1[6] += u1.z; S1[7] += u1.w;
    S2[0] += w0.x; S2[1] += w0.y; S2[2] += w0.z; S2[3] += w0.w;
    S2[4] += w1.x; S2[5] += w1.y; S2[6] += w1.z; S2[7] += w1.w;
  }
  float mu[8], i2v[8];
  float lacc = 0.f;
#pragma unroll
  for (int k = 0; k < 8; ++k) {
    mu[k] = S1[k] * inv_den;
    float var = (S2[k] - 2.0f * mu[k] * S1[k] + mu[k] * mu[k] * S0) * inv_den;
    var = fmaxf(var, 0.0f);
    i2v[k] = 1.0f / (2.0f * var + EPSF);
    lacc += logf(var + EPSF);
  }
  *(float4*)&mu_s[n * 2048 + t * 8]      = make_float4(mu[0], mu[1], mu[2], mu[3]);
  *(float4*)&mu_s[n * 2048 + t * 8 + 4]  = make_float4(mu[4], mu[5], mu[6], mu[7]);
  *(float4*)&i2v_s[n * 2048 + t * 8]     = make_float4(i2v[0], i2v[1], i2v[2], i2v[3]);
  *(float4*)&i2v_s[n * 2048 + t * 8 + 4] = make_float4(i2v[4], i2v[5], i2v[6], i2v[7]);
  lacc += __shfl_xor(lacc, 1);
  lacc += __shfl_xor(lacc, 2);
  lacc += __shfl_xor(lacc, 4);
  const float bI = beta_ign[o];
  const float aout = BUsum * (1.0f / NO) - bI * (Fsum - S0);
  const float lsg = fminf(aout, 0.0f) - log1pf(__expf(-fabsf(aout)));
  if (q == 0) cterm[n * NO + o] = lsg - 0.5f * lacc;
}

// ---------------- k3: fused log_p -> softmax(R over o) -> em accumulate.
// Barrier-free: lane = (o:32, h:2 j-halves); softmax over o is in-wave shfl.
// grid 256 = (nb:16, c:16); wave w handles n = nb*4+w, l in [c*8, c*8+8).
__global__ __launch_bounds__(256) void k3_em(
    const float* __restrict__ V, const float* __restrict__ f_a,
    const float* __restrict__ beta_use, const float* __restrict__ mu_s,
    const float* __restrict__ i2v_s, const float* __restrict__ cterm,
    float* __restrict__ S1p, float* __restrict__ S2p,
    float* __restrict__ dnp, float* __restrict__ aUp)
{
  const int nb = blockIdx.x >> 4;
  const int c  = blockIdx.x & 15;
  const int w  = threadIdx.x >> 6;
  const int lane = threadIdx.x & 63;
  const int n = nb * 4 + w;
  const int o = lane & 31;
  const int h = lane >> 5;
  const int jb = h * 32;

  float mu[32], iv[32];
  {
    const float* mb = mu_s  + n * 2048 + o * 64 + jb;
    const float* vb = i2v_s + n * 2048 + o * 64 + jb;
#pragma unroll
    for (int g = 0; g < 8; ++g) {
      const float4 m4 = *(const float4*)&mb[4 * g];
      const float4 v4 = *(const float4*)&vb[4 * g];
      mu[4 * g + 0] = m4.x; mu[4 * g + 1] = m4.y; mu[4 * g + 2] = m4.z; mu[4 * g + 3] = m4.w;
      iv[4 * g + 0] = v4.x; iv[4 * g + 1] = v4.y; iv[4 * g + 2] = v4.z; iv[4 * g + 3] = v4.w;
    }
  }
  const float ct = cterm[n * NO + o];
  float S1[32], S2[32];
#pragma unroll
  for (int k = 0; k < 32; ++k) { S1[k] = 0.f; S2[k] = 0.f; }
  float dn = 0.f, aU = 0.f;

  const int l0 = c * 8;
  float Va[32], Vb[32];
#define LOADV(buf, l)                                                         \
  {                                                                           \
    const float* vr = V + ((size_t)n * LL + (l)) * 2048 + o * 64 + jb;        \
    _Pragma("unroll")                                                         \
    for (int g = 0; g < 8; ++g) {                                             \
      const float4 q4 = *(const float4*)&vr[4 * g];                           \
      buf[4 * g + 0] = q4.x; buf[4 * g + 1] = q4.y;                           \
      buf[4 * g + 2] = q4.z; buf[4 * g + 3] = q4.w;                           \
    }                                                                         \
  }
#define PROC(buf, l)                                                          \
  {                                                                           \
    const float fa = f_a[(l)*NB + n];                                         \
    const float bu = beta_use[(l)];                                           \
    float s2 = 0.f;                                                           \
    _Pragma("unroll")                                                         \
    for (int k = 0; k < 32; ++k) {                                            \
      const float d = buf[k] - mu[k];                                         \
      s2 = fmaf(d * iv[k], d, s2);                                            \
    }                                                                         \
    s2 += __shfl_xor(s2, 32);                                                 \
    const float tt = ct - s2;                                                 \
    float m = tt;                                                             \
    m = fmaxf(m, __shfl_xor(m, 1));                                           \
    m = fmaxf(m, __shfl_xor(m, 2));                                           \
    m = fmaxf(m, __shfl_xor(m, 4));                                           \
    m = fmaxf(m, __shfl_xor(m, 8));                                           \
    m = fmaxf(m, __shfl_xor(m, 16));                                          \
    const float e = __expf(tt - m);                                           \
    float z = e;                                                              \
    z += __shfl_xor(z, 1);                                                    \
    z += __shfl_xor(z, 2);                                                    \
    z += __shfl_xor(z, 4);                                                    \
    z += __shfl_xor(z, 8);                                                    \
    z += __shfl_xor(z, 16);                                                   \
    const float wgt = fa * e / z;                                             \
    dn += wgt;                                                                \
    aU = fmaf(bu, wgt, aU);                                                   \
    _Pragma("unroll")                                                         \
    for (int k = 0; k < 32; ++k) {                                            \
      S1[k] = fmaf(wgt, buf[k], S1[k]);                                       \
      const float d = buf[k] - mu[k];                                         \
      S2[k] = fmaf(wgt * d, d, S2[k]);                                        \
    }                                                                         \
  }

  LOADV(Va, l0);
#pragma unroll
  for (int li = 0; li < 8; li += 2) {
    if (li + 1 < 8) LOADV(Vb, l0 + li + 1);
    PROC(Va, l0 + li);
    if (li + 2 < 8) LOADV(Va, l0 + li + 2);
    if (li + 1 < 8) PROC(Vb, l0 + li + 1);
  }
#undef LOADV
#undef PROC

  {
    float* s1b = S1p + ((size_t)(c * NB + n) * NO + o) * OD + jb;
    float* s2b = S2p + ((size_t)(c * NB + n) * NO + o) * OD + jb;
#pragma unroll
    for (int g = 0; g < 8; ++g) {
      *(float4*)&s1b[4 * g] = make_float4(S1[4 * g], S1[4 * g + 1], S1[4 * g + 2], S1[4 * g + 3]);
      *(float4*)&s2b[4 * g] = make_float4(S2[4 * g], S2[4 * g + 1], S2[4 * g + 2], S2[4 * g + 3]);
    }
  }
  if (h == 0) {
    dnp[(c * NB + n) * NO + o] = dn;
    aUp[(c * NB + n) * NO + o] = aU;
  }
}

// ---------------- k4: finalize iters 2/3 (shifted-variance around mu_prev)
__global__ __launch_bounds__(256) void k4_fin23(
    const float* __restrict__ S1p, const float* __restrict__ S2p,
    const float* __restrict__ dnp, const float* __restrict__ aUp,
    const float* __restrict__ f_a, const float* __restrict__ beta_ign,
    float* __restrict__ mu_s, float* __restrict__ i2v_s, float* __restrict__ cterm,
    float* __restrict__ out, const int final_iter)
{
  const int n = blockIdx.x;
  const int t = threadIdx.x;
  const int o = t >> 3, q = t & 7;
  const int j0 = q * 8;
  __shared__ float rA[128];
  if (t < 128) rA[t] = f_a[t * NB + n];
  __syncthreads();
  for (int s = 64; s >= 1; s >>= 1) {
    if (t < s) rA[t] += rA[t + s];
    __syncthreads();
  }
  const float Fsum = rA[0];

  float dn = 0.f, aU = 0.f;
#pragma unroll
  for (int cc = 0; cc < 16; ++cc) {
    dn += dnp[(cc * NB + n) * NO + o];
    aU += aUp[(cc * NB + n) * NO + o];
  }
  const float S0 = dn;
  const float denom = dn + EPSF;
  const float inv_den = 1.0f / denom;

  float S1[8], S2[8];
#pragma unroll
  for (int k = 0; k < 8; ++k) { S1[k] = 0.f; S2[k] = 0.f; }
  for (int cc = 0; cc < 16; ++cc) {
    const int base = ((cc * NB + n) * NO + o) * OD + j0;
    const float4 u0 = *(const float4*)&S1p[base];
    const float4 u1 = *(const float4*)&S1p[base + 4];
    const float4 w0 = *(const float4*)&S2p[base];
    const float4 w1 = *(const float4*)&S2p[base + 4];
    S1[0] += u0.x; S1[1] += u0.y; S1[2] += u0.z; S1[3] += u0.w;
    S1[4] += u1.x; S1[5] += u1.y; S1[6] += u1.z; S1[7] += u1.w;
    S2[0] += w0.x; S2[1] += w0.y; S2[2] += w0.z; S2[3] += w0.w;
    S2[4] += w1.x; S2[5] += w1.y; S2[6] += w1.z; S2[7] += w1.w;
  }
  float mup[8];
  {
    const float4 a0 = *(const float4*)&mu_s[n * 2048 + t * 8];
    const float4 a1 = *(const float4*)&mu_s[n * 2048 + t * 8 + 4];
    mup[0] = a0.x; mup[1] = a0.y; mup[2] = a0.z; mup[3] = a0.w;
    mup[4] = a1.x; mup[5] = a1.y; mup[6] = a1.z; mup[7] = a1.w;
  }
  const float aout = aU - beta_ign[o] * (Fsum - dn);

  float mu[8], i2v[8];
  float lacc = 0.f;
#pragma unroll
  for (int k = 0; k < 8; ++k) {
    mu[k] = S1[k] * inv_den;
    const float dd = mu[k] - mup[k];
    float varn = S2[k] - 2.0f * dd * (S1[k] - mup[k] * S0) + dd * dd * S0;
    float var = fmaxf(varn * inv_den, 0.0f);
    i2v[k] = 1.0f / (2.0f * var + EPSF);
    lacc += logf(var + EPSF);
  }
  if (final_iter) {
    if (q == 0) out[n * NO + o] = aout;
    *(float4*)&out[2048 + n * 2048 + t * 8]     = make_float4(mu[0], mu[1], mu[2], mu[3]);
    *(float4*)&out[2048 + n * 2048 + t * 8 + 4] = make_float4(mu[4], mu[5], mu[6], mu[7]);
  } else {
    *(float4*)&mu_s[n * 2048 + t * 8]      = make_float4(mu[0], mu[1], mu[2], mu[3]);
    *(float4*)&mu_s[n * 2048 + t * 8 + 4]  = make_float4(mu[4], mu[5], mu[6], mu[7]);
    *(float4*)&i2v_s[n * 2048 + t * 8]     = make_float4(i2v[0], i2v[1], i2v[2], i2v[3]);
    *(float4*)&i2v_s[n * 2048 + t * 8 + 4] = make_float4(i2v[4], i2v[5], i2v[6], i2v[7]);
    lacc += __shfl_xor(lacc, 1);
    lacc += __shfl_xor(lacc, 2);
    lacc += __shfl_xor(lacc, 4);
    const float lsg = fminf(aout, 0.0f) - log1pf(__expf(-fabsf(aout)));
    if (q == 0) cterm[n * NO + o] = lsg - 0.5f * lacc;
  }
}

extern "C" void kernel_launch(void* const* d_in, const int* in_sizes, int n_in,
                              void* d_out, int out_size, void* d_ws, size_t ws_size,
                              hipStream_t stream) {
  const float* x        = (const float*)d_in[0];
  const float* Wscore   = (const float*)d_in[1];
  const float* Bscore   = (const float*)d_in[2];
  const float* Wcap     = (const float*)d_in[3];
  const float* Bcap     = (const float*)d_in[4];
  const float* Wvote    = (const float*)d_in[5];
  const float* Bvote    = (const float*)d_in[6];
  const float* beta_use = (const float*)d_in[7];
  const float* beta_ign = (const float*)d_in[8];
  // d_in[9] = iters (fixed at 3 by setup; graph capture forbids readback)
  float* out = (float*)d_out;

  float* ws      = (float*)d_ws;
  float* V       = ws;                        // 16777216
  float* Cpart   = ws;                        // aliases V (pre-k1)
  float* apart   = ws + 3145728;              // aliases V (pre-k1)
  float* mu_in_T = ws + 16777216;             // 524288 (dead after k1)
  float* dnp     = mu_in_T;                   // 32768  (aliases; post-k1)
  float* aUp     = mu_in_T + 32768;           // 32768  (aliases; post-k1)
  float* f_a     = mu_in_T + 524288;          // 8192
  float* S1p     = f_a + 8192;                // 2097152
  float* S2p     = S1p + 2097152;             // 2097152
  float* mu_s    = S2p + 2097152;             // 131072
  float* i2v_s   = mu_s + 131072;             // 131072
  float* ct      = i2v_s + 131072;            // 2048
  const size_t need = (size_t)(16777216 + 524288 + 8192 + 2 * 2097152 +
                               2 * 131072 + 2048) * sizeof(float);
  if (ws_size < need) return;

  k0a_proj<<<768, 256, 0, stream>>>(x, Wscore, Wcap, Cpart, apart);
  k0b_reduce<<<128, 256, 0, stream>>>(Cpart, Bcap, mu_in_T);
  k0c_fa<<<32, 256, 0, stream>>>(apart, Bscore, f_a);
  k1_votes<<<512, 256, 0, stream>>>(mu_in_T, Wvote, Bvote, f_a, V, S1p, S2p);
  k2_fin1<<<64, 256, 0, stream>>>(S1p, S2p, f_a, beta_use, beta_ign, mu_s, i2v_s, ct);
  // iter 2
  k3_em<<<256, 256, 0, stream>>>(V, f_a, beta_use, mu_s, i2v_s, ct, S1p, S2p, dnp, aUp);
  k4_fin23<<<64, 256, 0, stream>>>(S1p, S2p, dnp, aUp, f_a, beta_ign, mu_s, i2v_s, ct, out, 0);
  // iter 3 (final)
  k3_em<<<256, 256, 0, stream>>>(V, f_a, beta_use, mu_s, i2v_s, ct, S1p, S2p, dnp, aUp);
  k4_fin23<<<64, 256, 0, stream>>>(S1p, S2p, dnp, aUp, f_a, beta_ign, mu_s, i2v_s, ct, out, 1);
}

// Round 6
// 247.270 us; speedup vs baseline: 1.2357x; 1.2357x over previous
//
#include <hip/hip_runtime.h>
#include <math.h>

#define NB 64      // batch N
#define LL 128     // n_in capsules
#define DD 768     // feature dim
#define ID 64      // in_dim
#define OD 64      // out_dim
#define NO 32      // n_out
#define EPSF 1e-8f

typedef unsigned short ushort_t;
typedef __attribute__((ext_vector_type(8))) short bf16x8;
typedef __attribute__((ext_vector_type(4))) float f32x4;

// ws layout (floats):
//  V     : NB*LL*NO*OD = 16777216 fp32  [n][l][o*64+j]
//    Cpart: 6*524288 = 3145728 (aliases V front; consumed pre-k1)
//    apart: 6*8192   = 49152   (aliases V;       consumed pre-k1)
//  Ah/Al : 2 x 524288 ushorts = 524288 floats   dual-bf16 mu_in [l][n][i]
//  f_a   : 8192
//  S1p   : 8*NB*NO*OD = 1048576   chunk partials [c][n][o][j]
//  S2p   : 1048576
//  dnp   : 8*NB*NO = 16384 ; aUp : 16384
//  mu_s  : 131072 ; i2v_s : 131072 ; cterm : 2048

__device__ __forceinline__ float gelu_exact(float v) {
  return 0.5f * v * (1.0f + erff(v * 0.70710678118654752440f));
}
__device__ __forceinline__ float sigmoidf_(float z) {
  return 1.0f / (1.0f + __expf(-z));
}
__device__ __forceinline__ unsigned short f2bf(float f) {  // RNE
  unsigned u = __float_as_uint(f);
  unsigned r = (u + 0x7FFFu + ((u >> 16) & 1u)) >> 16;
  return (unsigned short)r;
}
__device__ __forceinline__ float bf2f(unsigned short s) {
  return __uint_as_float(((unsigned)s) << 16);
}

// ---------------- k0a: split-K partial GEMM for the projections (unchanged).
__global__ __launch_bounds__(256) void k0a_proj(
    const float* __restrict__ x, const float* __restrict__ Wscore,
    const float* __restrict__ Wcap,
    float* __restrict__ Cpart, float* __restrict__ apart)
{
  const int l  = blockIdx.x & 127;
  const int kc = blockIdx.x >> 7;
  const int t = threadIdx.x;
  const int tn = t >> 4;
  const int ti = t & 15;
  __shared__ float Xs[64][68];
  __shared__ float Ws[64][68];
  __shared__ float Ss[64];
  float C[4][4] = {{0.f}};
  float asum[4] = {0.f, 0.f, 0.f, 0.f};

  for (int kt = 0; kt < 2; ++kt) {
    const int kbase = kc * 128 + kt * 64;
#pragma unroll
    for (int r = 0; r < 4; ++r) {
      const int flat = r * 1024 + t * 4;
      const int p = flat >> 6, qq = flat & 63;
      *(float4*)&Xs[p][qq] = *(const float4*)&x[(p * LL + l) * DD + kbase + qq];
      *(float4*)&Ws[p][qq] = *(const float4*)&Wcap[(l * DD + kbase + p) * ID + qq];
    }
    if (t < 16)
      *(float4*)&Ss[4 * t] = *(const float4*)&Wscore[l * DD + kbase + 4 * t];
    __syncthreads();
#pragma unroll 8
    for (int k = 0; k < 64; ++k) {
      float av[4];
      av[0] = Xs[4 * tn + 0][k];
      av[1] = Xs[4 * tn + 1][k];
      av[2] = Xs[4 * tn + 2][k];
      av[3] = Xs[4 * tn + 3][k];
      const float4 b = *(const float4*)&Ws[k][4 * ti];
      const float sk = Ss[k];
#pragma unroll
      for (int a = 0; a < 4; ++a) {
        C[a][0] = fmaf(av[a], b.x, C[a][0]);
        C[a][1] = fmaf(av[a], b.y, C[a][1]);
        C[a][2] = fmaf(av[a], b.z, C[a][2]);
        C[a][3] = fmaf(av[a], b.w, C[a][3]);
        asum[a] = fmaf(av[a], sk, asum[a]);
      }
    }
    __syncthreads();
  }
#pragma unroll
  for (int a = 0; a < 4; ++a)
    *(float4*)&Cpart[kc * 524288 + (l * 64 + 4 * tn + a) * 64 + 4 * ti] =
        make_float4(C[a][0], C[a][1], C[a][2], C[a][3]);
  if (ti == 0) {   // asum complete per K-slice in every ti-thread; no reduce
#pragma unroll
    for (int a = 0; a < 4; ++a)
      apart[kc * 8192 + l * 64 + 4 * tn + a] = asum[a];
  }
}

// ---------------- k0b: reduce partials + bias + gelu -> dual-bf16 mu_in
__global__ __launch_bounds__(256) void k0b_reduce(
    const float* __restrict__ Cpart, const float* __restrict__ Bcap,
    ushort_t* __restrict__ Ah, ushort_t* __restrict__ Al)
{
  const int e = (blockIdx.x * 256 + threadIdx.x) * 4;
  float4 s = *(const float4*)&Cpart[e];
#pragma unroll
  for (int kc = 1; kc < 6; ++kc) {
    const float4 p = *(const float4*)&Cpart[kc * 524288 + e];
    s.x += p.x; s.y += p.y; s.z += p.z; s.w += p.w;
  }
  const int l = e >> 12;
  const int col = e & 63;
  const float4 bc = *(const float4*)&Bcap[l * 64 + col];
  float m[4] = {gelu_exact(s.x + bc.x), gelu_exact(s.y + bc.y),
                gelu_exact(s.z + bc.z), gelu_exact(s.w + bc.w)};
  ushort4 h, lo;
  h.x = f2bf(m[0]); lo.x = f2bf(m[0] - bf2f(h.x));
  h.y = f2bf(m[1]); lo.y = f2bf(m[1] - bf2f(h.y));
  h.z = f2bf(m[2]); lo.z = f2bf(m[2] - bf2f(h.z));
  h.w = f2bf(m[3]); lo.w = f2bf(m[3] - bf2f(h.w));
  *(ushort4*)&Ah[e] = h;
  *(ushort4*)&Al[e] = lo;
}

// ---------------- k0c: reduce asum partials + Bscore -> f_a (sigmoid)
__global__ __launch_bounds__(256) void k0c_fa(
    const float* __restrict__ apart, const float* __restrict__ Bscore,
    float* __restrict__ f_a)
{
  const int e = blockIdx.x * 256 + threadIdx.x;
  float s = 0.f;
#pragma unroll
  for (int kc = 0; kc < 6; ++kc) s += apart[kc * 8192 + e];
  const int l = e >> 6;
  f_a[e] = sigmoidf_(s + Bscore[l]);
}

// ---------------- k1: V = mu_in @ Wvote + Bvote via split-bf16 MFMA (3-term).
// One wave per (l,o); Wvote tile converted to hi/lo bf16 in wave-private LDS.
// grid 1024 x 256 (4 waves/block). Fragment/output indexing = R4-validated.
__global__ __launch_bounds__(256) void k1_votes(
    const ushort_t* __restrict__ Ah, const ushort_t* __restrict__ Al,
    const float* __restrict__ Wvote, const float* __restrict__ Bvote,
    float* __restrict__ V)
{
  const int t = threadIdx.x;
  const int w = t >> 6;
  const int lane = t & 63;
  const int pair = blockIdx.x * 4 + w;    // l*NO + o
  const int l = pair >> 5;
  const int mr = lane & 15, q = lane >> 4;

  __shared__ unsigned HL_all[4][4096];    // per-wave [k=i][j] hi|lo<<16
  unsigned* HL = HL_all[w];

  // A fragments (hi/lo) straight from global (L2-resident, k-contiguous)
  bf16x8 afh[2][4], afl[2][4];
#pragma unroll
  for (int ks = 0; ks < 2; ++ks)
#pragma unroll
    for (int mt = 0; mt < 4; ++mt) {
      const int off = l * 4096 + (16 * mt + mr) * 64 + ks * 32 + q * 8;
      afh[ks][mt] = *(const bf16x8*)&Ah[off];
      afl[ks][mt] = *(const bf16x8*)&Al[off];
    }

  // stage Wvote (l,o) tile: coalesced float4 rows -> hi/lo packed u32 LDS
  const float* Wt = Wvote + (size_t)pair * 4096;   // [i][j]
#pragma unroll
  for (int f = 0; f < 16; ++f) {
    const float4 v4 = *(const float4*)&Wt[f * 256 + lane * 4];
    const int i = f * 4 + q;             // k-row
    const int j0 = mr * 4;
    const float e4[4] = {v4.x, v4.y, v4.z, v4.w};
    unsigned pk[4];
#pragma unroll
    for (int d = 0; d < 4; ++d) {
      const unsigned short hi = f2bf(e4[d]);
      const unsigned short lo = f2bf(e4[d] - bf2f(hi));
      pk[d] = (unsigned)hi | ((unsigned)lo << 16);
    }
    *(uint4*)&HL[i * 64 + j0] = make_uint4(pk[0], pk[1], pk[2], pk[3]);
  }
  // wave-private LDS: no barrier needed (compiler inserts lgkmcnt waits)

  f32x4 acc[4][4];
#pragma unroll
  for (int mt = 0; mt < 4; ++mt)
#pragma unroll
    for (int nt = 0; nt < 4; ++nt) {
      f32x4 z = {0.f, 0.f, 0.f, 0.f};
      acc[mt][nt] = z;
    }

#pragma unroll
  for (int ks = 0; ks < 2; ++ks)
#pragma unroll
    for (int nt = 0; nt < 4; ++nt) {
      const int j = 16 * nt + mr;
      const int i0 = ks * 32 + q * 8;
      unsigned wv[8];
#pragma unroll
      for (int d = 0; d < 8; ++d) wv[d] = HL[(i0 + d) * 64 + j];
      union { ushort_t u[8]; bf16x8 v; } bh, bl;
#pragma unroll
      for (int d = 0; d < 8; ++d) {
        bh.u[d] = (ushort_t)(wv[d] & 0xffffu);
        bl.u[d] = (ushort_t)(wv[d] >> 16);
      }
#pragma unroll
      for (int mt = 0; mt < 4; ++mt) {
        acc[mt][nt] = __builtin_amdgcn_mfma_f32_16x16x32_bf16(
            afh[ks][mt], bh.v, acc[mt][nt], 0, 0, 0);
        acc[mt][nt] = __builtin_amdgcn_mfma_f32_16x16x32_bf16(
            afh[ks][mt], bl.v, acc[mt][nt], 0, 0, 0);
        acc[mt][nt] = __builtin_amdgcn_mfma_f32_16x16x32_bf16(
            afl[ks][mt], bh.v, acc[mt][nt], 0, 0, 0);
      }
    }

  float bv[4];
#pragma unroll
  for (int nt = 0; nt < 4; ++nt) bv[nt] = Bvote[pair * 64 + 16 * nt + mr];

#pragma unroll
  for (int mt = 0; mt < 4; ++mt)
#pragma unroll
    for (int r = 0; r < 4; ++r) {
      const int n = 16 * mt + 4 * q + r;
      const size_t base = (size_t)n * (LL * NO * OD) + (size_t)pair * 64;
#pragma unroll
      for (int nt = 0; nt < 4; ++nt)
        V[base + 16 * nt + mr] = acc[mt][nt][r] + bv[nt];
    }
}

// ---------------- k3: fused log_p -> softmax(R over o) -> em accumulate.
// mode 0: uniform R=1/NO (iter 1).  grid 512 = (n:64, c:8 of 16 l's).
// R4-validated structure, fp32 V.
__global__ __launch_bounds__(256) void k3_em(
    const float* __restrict__ V, const float* __restrict__ f_a,
    const float* __restrict__ beta_use, const float* __restrict__ mu_s,
    const float* __restrict__ i2v_s, const float* __restrict__ cterm,
    float* __restrict__ S1p, float* __restrict__ S2p,
    float* __restrict__ dnp, float* __restrict__ aUp, const int mode)
{
  const int n = blockIdx.x >> 3;
  const int c = blockIdx.x & 7;
  const int t = threadIdx.x;
  const int o = t >> 3, q = t & 7;
  __shared__ float ttl[8][32];

  float mu8[8], iv8[8];
  float ct = 0.f;
  if (mode) {
    const float4 a0 = *(const float4*)&mu_s[n * 2048 + t * 8];
    const float4 a1 = *(const float4*)&mu_s[n * 2048 + t * 8 + 4];
    mu8[0] = a0.x; mu8[1] = a0.y; mu8[2] = a0.z; mu8[3] = a0.w;
    mu8[4] = a1.x; mu8[5] = a1.y; mu8[6] = a1.z; mu8[7] = a1.w;
    const float4 b0 = *(const float4*)&i2v_s[n * 2048 + t * 8];
    const float4 b1 = *(const float4*)&i2v_s[n * 2048 + t * 8 + 4];
    iv8[0] = b0.x; iv8[1] = b0.y; iv8[2] = b0.z; iv8[3] = b0.w;
    iv8[4] = b1.x; iv8[5] = b1.y; iv8[6] = b1.z; iv8[7] = b1.w;
    ct = cterm[n * NO + o];
  }
  float aS1[8] = {0.f, 0.f, 0.f, 0.f, 0.f, 0.f, 0.f, 0.f};
  float aS2[8] = {0.f, 0.f, 0.f, 0.f, 0.f, 0.f, 0.f, 0.f};
  float dn = 0.f, aU = 0.f;

  for (int g = 0; g < 4; ++g) {
    const int lb = c * 16 + g * 4;
    float Vv[4][8], fa4[4], bu4[4], tt4[4];
#pragma unroll
    for (int u = 0; u < 4; ++u) {
      const int l = lb + u;
      const float4 v0 = *(const float4*)&V[((size_t)n * LL + l) * 2048 + t * 8];
      const float4 v1 = *(const float4*)&V[((size_t)n * LL + l) * 2048 + t * 8 + 4];
      Vv[u][0] = v0.x; Vv[u][1] = v0.y; Vv[u][2] = v0.z; Vv[u][3] = v0.w;
      Vv[u][4] = v1.x; Vv[u][5] = v1.y; Vv[u][6] = v1.z; Vv[u][7] = v1.w;
      fa4[u] = f_a[l * NB + n];
      bu4[u] = beta_use[l];
    }
    if (mode) {
#pragma unroll
      for (int u = 0; u < 4; ++u) {
        float s2 = 0.f;
#pragma unroll
        for (int k = 0; k < 8; ++k) {
          const float d = Vv[u][k] - mu8[k];
          s2 = fmaf(d * d, iv8[k], s2);
        }
        s2 += __shfl_xor(s2, 1);
        s2 += __shfl_xor(s2, 2);
        s2 += __shfl_xor(s2, 4);
        tt4[u] = ct - s2;
      }
      const int sb = (g & 1) * 4;
      if (q == 0) {
#pragma unroll
        for (int u = 0; u < 4; ++u) ttl[sb + u][o] = tt4[u];
      }
      __syncthreads();
#pragma unroll
      for (int u = 0; u < 4; ++u) {
        const float vv = ttl[sb + u][t & 31];
        float m = vv;
#pragma unroll
        for (int msk = 1; msk <= 16; msk <<= 1) m = fmaxf(m, __shfl_xor(m, msk));
        float z = __expf(vv - m);
#pragma unroll
        for (int msk = 1; msk <= 16; msk <<= 1) z += __shfl_xor(z, msk);
        const float wgt = fa4[u] * __expf(tt4[u] - m) / z;
        dn += wgt;
        aU = fmaf(bu4[u], wgt, aU);
#pragma unroll
        for (int k = 0; k < 8; ++k) {
          const float d = Vv[u][k] - mu8[k];
          aS1[k] = fmaf(wgt, Vv[u][k], aS1[k]);
          aS2[k] = fmaf(wgt, d * d, aS2[k]);   // shifted around mu_prev
        }
      }
    } else {
#pragma unroll
      for (int u = 0; u < 4; ++u) {
        const float wgt = fa4[u] * (1.0f / NO);
        dn += wgt;
        aU = fmaf(bu4[u], wgt, aU);
#pragma unroll
        for (int k = 0; k < 8; ++k) {
          aS1[k] = fmaf(wgt, Vv[u][k], aS1[k]);
          aS2[k] = fmaf(wgt * Vv[u][k], Vv[u][k], aS2[k]);
        }
      }
    }
  }
  const int base = ((c * NB + n) * NO + o) * OD + q * 8;
  *(float4*)&S1p[base]     = make_float4(aS1[0], aS1[1], aS1[2], aS1[3]);
  *(float4*)&S1p[base + 4] = make_float4(aS1[4], aS1[5], aS1[6], aS1[7]);
  *(float4*)&S2p[base]     = make_float4(aS2[0], aS2[1], aS2[2], aS2[3]);
  *(float4*)&S2p[base + 4] = make_float4(aS2[4], aS2[5], aS2[6], aS2[7]);
  if (q == 0) {
    dnp[(c * NB + n) * NO + o] = dn;
    aUp[(c * NB + n) * NO + o] = aU;
  }
}

// ---------------- k4: finalize (shifted-variance; first iter uses mup=0)
__global__ __launch_bounds__(256) void k4_fin23(
    const float* __restrict__ S1p, const float* __restrict__ S2p,
    const float* __restrict__ dnp, const float* __restrict__ aUp,
    const float* __restrict__ f_a, const float* __restrict__ beta_ign,
    float* __restrict__ mu_s, float* __restrict__ i2v_s, float* __restrict__ cterm,
    float* __restrict__ out, const int final_iter, const int first)
{
  const int n = blockIdx.x;
  const int t = threadIdx.x;
  const int o = t >> 3, q = t & 7;
  const int j0 = q * 8;
  __shared__ float rA[128];
  if (t < 128) rA[t] = f_a[t * NB + n];
  __syncthreads();
  for (int s = 64; s >= 1; s >>= 1) {
    if (t < s) rA[t] += rA[t + s];
    __syncthreads();
  }
  const float Fsum = rA[0];

  float dn = 0.f, aU = 0.f;
#pragma unroll
  for (int cc = 0; cc < 8; ++cc) {
    dn += dnp[(cc * NB + n) * NO + o];
    aU += aUp[(cc * NB + n) * NO + o];
  }
  const float S0 = dn;
  const float denom = dn + EPSF;
  const float inv_den = 1.0f / denom;

  float S1[8], S2[8];
#pragma unroll
  for (int k = 0; k < 8; ++k) { S1[k] = 0.f; S2[k] = 0.f; }
  for (int cc = 0; cc < 8; ++cc) {
    const int base = ((cc * NB + n) * NO + o) * OD + j0;
    const float4 u0 = *(const float4*)&S1p[base];
    const float4 u1 = *(const float4*)&S1p[base + 4];
    const float4 w0 = *(const float4*)&S2p[base];
    const float4 w1 = *(const float4*)&S2p[base + 4];
    S1[0] += u0.x; S1[1] += u0.y; S1[2] += u0.z; S1[3] += u0.w;
    S1[4] += u1.x; S1[5] += u1.y; S1[6] += u1.z; S1[7] += u1.w;
    S2[0] += w0.x; S2[1] += w0.y; S2[2] += w0.z; S2[3] += w0.w;
    S2[4] += w1.x; S2[5] += w1.y; S2[6] += w1.z; S2[7] += w1.w;
  }
  float mup[8];
  if (first) {
#pragma unroll
    for (int k = 0; k < 8; ++k) mup[k] = 0.f;
  } else {
    const float4 a0 = *(const float4*)&mu_s[n * 2048 + t * 8];
    const float4 a1 = *(const float4*)&mu_s[n * 2048 + t * 8 + 4];
    mup[0] = a0.x; mup[1] = a0.y; mup[2] = a0.z; mup[3] = a0.w;
    mup[4] = a1.x; mup[5] = a1.y; mup[6] = a1.z; mup[7] = a1.w;
  }
  const float aout = aU - beta_ign[o] * (Fsum - dn);

  float mu[8], i2v[8];
  float lacc = 0.f;
#pragma unroll
  for (int k = 0; k < 8; ++k) {
    mu[k] = S1[k] * inv_den;
    const float dd = mu[k] - mup[k];
    float varn = S2[k] - 2.0f * dd * (S1[k] - mup[k] * S0) + dd * dd * S0;
    float var = fmaxf(varn * inv_den, 0.0f);
    i2v[k] = 1.0f / (2.0f * var + EPSF);
    lacc += logf(var + EPSF);
  }
  if (final_iter) {
    if (q == 0) out[n * NO + o] = aout;
    *(float4*)&out[2048 + n * 2048 + t * 8]     = make_float4(mu[0], mu[1], mu[2], mu[3]);
    *(float4*)&out[2048 + n * 2048 + t * 8 + 4] = make_float4(mu[4], mu[5], mu[6], mu[7]);
  } else {
    *(float4*)&mu_s[n * 2048 + t * 8]      = make_float4(mu[0], mu[1], mu[2], mu[3]);
    *(float4*)&mu_s[n * 2048 + t * 8 + 4]  = make_float4(mu[4], mu[5], mu[6], mu[7]);
    *(float4*)&i2v_s[n * 2048 + t * 8]     = make_float4(i2v[0], i2v[1], i2v[2], i2v[3]);
    *(float4*)&i2v_s[n * 2048 + t * 8 + 4] = make_float4(i2v[4], i2v[5], i2v[6], i2v[7]);
    lacc += __shfl_xor(lacc, 1);
    lacc += __shfl_xor(lacc, 2);
    lacc += __shfl_xor(lacc, 4);
    const float lsg = fminf(aout, 0.0f) - log1pf(__expf(-fabsf(aout)));
    if (q == 0) cterm[n * NO + o] = lsg - 0.5f * lacc;
  }
}

extern "C" void kernel_launch(void* const* d_in, const int* in_sizes, int n_in,
                              void* d_out, int out_size, void* d_ws, size_t ws_size,
                              hipStream_t stream) {
  const float* x        = (const float*)d_in[0];
  const float* Wscore   = (const float*)d_in[1];
  const float* Bscore   = (const float*)d_in[2];
  const float* Wcap     = (const float*)d_in[3];
  const float* Bcap     = (const float*)d_in[4];
  const float* Wvote    = (const float*)d_in[5];
  const float* Bvote    = (const float*)d_in[6];
  const float* beta_use = (const float*)d_in[7];
  const float* beta_ign = (const float*)d_in[8];
  // d_in[9] = iters (fixed at 3 by setup; graph capture forbids readback)
  float* out = (float*)d_out;

  float* ws     = (float*)d_ws;
  float* V      = ws;                        // 16777216 fp32
  float* Cpart  = ws;                        // aliases V (pre-k1)
  float* apart  = ws + 3145728;              // aliases V (pre-k1)
  ushort_t* Ah  = (ushort_t*)(ws + 16777216);    // 524288 ushorts
  ushort_t* Al  = Ah + 524288;                   // 524288 ushorts
  float* f_a    = ws + 16777216 + 524288;    // 8192
  float* S1p    = f_a + 8192;                // 1048576
  float* S2p    = S1p + 1048576;             // 1048576
  float* dnp    = S2p + 1048576;             // 16384
  float* aUp    = dnp + 16384;               // 16384
  float* mu_s   = aUp + 16384;               // 131072
  float* i2v_s  = mu_s + 131072;             // 131072
  float* ct     = i2v_s + 131072;            // 2048
  const size_t need = (size_t)(16777216 + 524288 + 8192 + 2 * 1048576 +
                               2 * 16384 + 2 * 131072 + 2048) * sizeof(float);
  if (ws_size < need) return;

  k0a_proj<<<768, 256, 0, stream>>>(x, Wscore, Wcap, Cpart, apart);
  k0b_reduce<<<512, 256, 0, stream>>>(Cpart, Bcap, Ah, Al);
  k0c_fa<<<32, 256, 0, stream>>>(apart, Bscore, f_a);
  k1_votes<<<1024, 256, 0, stream>>>(Ah, Al, Wvote, Bvote, V);
  // iter 1 (uniform R)
  k3_em<<<512, 256, 0, stream>>>(V, f_a, beta_use, mu_s, i2v_s, ct, S1p, S2p, dnp, aUp, 0);
  k4_fin23<<<64, 256, 0, stream>>>(S1p, S2p, dnp, aUp, f_a, beta_ign, mu_s, i2v_s, ct, out, 0, 1);
  // iter 2
  k3_em<<<512, 256, 0, stream>>>(V, f_a, beta_use, mu_s, i2v_s, ct, S1p, S2p, dnp, aUp, 1);
  k4_fin23<<<64, 256, 0, stream>>>(S1p, S2p, dnp, aUp, f_a, beta_ign, mu_s, i2v_s, ct, out, 0, 0);
  // iter 3 (final)
  k3_em<<<512, 256, 0, stream>>>(V, f_a, beta_use, mu_s, i2v_s, ct, S1p, S2p, dnp, aUp, 1);
  k4_fin23<<<64, 256, 0, stream>>>(S1p, S2p, dnp, aUp, f_a, beta_ign, mu_s, i2v_s, ct, out, 1, 0);
}